// Round 5
// baseline (526.946 us; speedup 1.0000x reference)
//
#include <hip/hip_runtime.h>
#include <cstdint>
#include <cstddef>

// SummaryAdapter fused kernel for MI355X (gfx950), v5: v4 + explicit
// software pipelining (register double-buffers) to force memory-level
// parallelism the compiler refused to create (R4: 48 VGPR, ~2 loads in
// flight, 1.1 TB/s). L=8 B=2 S=4096 D=2048 N=128 Ds=1024 Da=64.
//
// Workspace layout (bytes):          off      size
//   KF  frag bf16                      0    262144
//   VF  frag bf16                 262144    262144
//   WqF frag bf16                 524288   2097152
//   WoF frag bf16                2621440   2097152
// Requires ws_size >= 4718592.

typedef __attribute__((ext_vector_type(8))) short short8;   // 8 x bf16 (4 VGPR)
typedef __attribute__((ext_vector_type(4))) float f32x4;

#define MFMA16(a, b, c) __builtin_amdgcn_mfma_f32_16x16x32_bf16((a), (b), (c), 0, 0, 0)

__device__ __forceinline__ unsigned short f2bf(float f) {
  unsigned int x = __builtin_bit_cast(unsigned int, f);
  x += 0x7fffu + ((x >> 16) & 1u);        // RNE
  return (unsigned short)(x >> 16);
}
__device__ __forceinline__ short8 cvt8v(f32x4 a, f32x4 b) {
  short8 r;
  r[0] = (short)f2bf(a[0]); r[1] = (short)f2bf(a[1]);
  r[2] = (short)f2bf(a[2]); r[3] = (short)f2bf(a[3]);
  r[4] = (short)f2bf(b[0]); r[5] = (short)f2bf(b[1]);
  r[6] = (short)f2bf(b[2]); r[7] = (short)f2bf(b[3]);
  return r;
}
__device__ __forceinline__ short8 ld_cvt8(const float* p) {
  f32x4 v0 = *(const f32x4*)p, v1 = *(const f32x4*)(p + 4);
  return cvt8v(v0, v1);
}

// ---------------- pre 1: K = bank@Wk^T, V = bank@Wv^T via MFMA -------------
__global__ __launch_bounds__(64)
void pre_kv_kernel(const float* __restrict__ bank,
                   const float* __restrict__ Wk,
                   const float* __restrict__ Wv,
                   unsigned short* __restrict__ KF, unsigned short* __restrict__ VF) {
  int bid = blockIdx.x;
  int nt = bid & 7, kv = (bid >> 3) & 1, b = (bid >> 4) & 1, l = bid >> 5;
  int lane = threadIdx.x & 63;
  int lo = lane & 15, hi = lane >> 4;
  const float* W  = (kv ? Wv : Wk) + (size_t)l * 65536;
  const float* bk = bank + (size_t)b * 131072;
  int lbq = l * 2 + b;
  f32x4 acc[4];
  #pragma unroll
  for (int at = 0; at < 4; ++at) acc[at] = (f32x4){0.f, 0.f, 0.f, 0.f};
  for (int ks = 0; ks < 32; ++ks) {
    short8 A = ld_cvt8(bk + (nt * 16 + lo) * 1024 + ks * 32 + hi * 8);
    #pragma unroll
    for (int at = 0; at < 4; ++at) {
      short8 B = ld_cvt8(W + (at * 16 + lo) * 1024 + ks * 32 + hi * 8);
      acc[at] = MFMA16(A, B, acc[at]);
    }
  }
  for (int at = 0; at < 4; ++at)
    for (int r = 0; r < 4; ++r) {
      int n = nt * 16 + hi * 4 + r;
      int a = at * 16 + lo;
      unsigned short v = f2bf(acc[at][r]);
      if (kv == 0) {
        int idx = ((lbq * 8 + (n >> 4)) * 2 + (a >> 5)) * 512 +
                  (((a >> 3) & 3) * 16 + (n & 15)) * 8 + (a & 7);
        KF[idx] = v;
      } else {
        int idx = ((lbq * 4 + (a >> 4)) * 4 + (n >> 5)) * 512 +
                  (((n >> 3) & 3) * 16 + (a & 15)) * 8 + (n & 7);
        VF[idx] = v;
      }
    }
}

// ---------------- pre 2: Wq/Wo -> bf16 fragment layout ---------------------
__global__ void pre_frag_kernel(const float* __restrict__ Wq, const float* __restrict__ Wo,
                                unsigned short* __restrict__ WqF, unsigned short* __restrict__ WoF) {
  int idx = blockIdx.x * 256 + threadIdx.x;        // 262144 threads
  if (idx < 131072) {
    int t = idx;
    int lane = t & 63, ks = (t >> 6) & 63, at = (t >> 12) & 3, l = t >> 14;
    int a = at * 16 + (lane & 15), d = ks * 32 + (lane >> 4) * 8;
    *(short8*)(WqF + (size_t)t * 8) = ld_cvt8(Wq + ((size_t)(l * 64 + a)) * 2048 + d);
  } else {
    int t = idx - 131072;
    int lane = t & 63, ks = (t >> 6) & 1, dt = (t >> 7) & 127, l = t >> 14;
    int d = dt * 16 + (lane & 15), a = ks * 32 + (lane >> 4) * 8;
    *(short8*)(WoF + (size_t)t * 8) = ld_cvt8(Wo + ((size_t)(l * 2048 + d)) * 64 + a);
  }
}

// ---------------- main fused kernel ----------------------------------------
// grid 1024 x 256 threads. Each WAVE owns one 16-row tile (4096 tiles, all
// co-resident at 4 blocks/CU, 16 waves/CU). No __syncthreads.
// Explicit register pipelines keep ~8-12 global loads in flight per wave.
__global__ __launch_bounds__(256, 4)
void adapter_main(const float* __restrict__ hidden,
                  const unsigned short* __restrict__ KF, const unsigned short* __restrict__ VF,
                  const unsigned short* __restrict__ WqF, const unsigned short* __restrict__ WoF,
                  const float* __restrict__ gates, float* __restrict__ out) {
  __shared__ float scratch[4][16 * 68];            // 4352 B per wave

  // XCD-bijective swizzle (1024 % 8 == 0): XCD x gets exactly layer x.
  int bid0 = blockIdx.x;
  int bid = (bid0 & 7) * 128 + (bid0 >> 3);
  int wave = threadIdx.x >> 6, lane = threadIdx.x & 63;
  int lo = lane & 15, hi = lane >> 4;
  int t = bid * 4 + wave;                          // tile id 0..4095
  int st = t & 255, b = (t >> 8) & 1, l = t >> 9;
  size_t hbase = ((size_t)(l * 2 + b) * 4096 + st * 16) * 2048;
  const float* hsrc = hidden + hbase;
  float gate = 1.0f / (1.0f + __expf(-gates[l]));
  float* qs = scratch[wave];
  unsigned short* qsu = (unsigned short*)qs;
  int lb = l * 2 + b;

  // ---- Phase 1: Q = h @ Wq^T, 4-deep k-step register pipeline ----
  {
    f32x4 qacc[4];
    #pragma unroll
    for (int at = 0; at < 4; ++at) qacc[at] = (f32x4){0.f, 0.f, 0.f, 0.f};
    const float* ap = hsrc + lo * 2048 + hi * 8;
    const unsigned short* wqb = WqF + ((size_t)l * 4 * 64) * 512 + lane * 8;
    f32x4 pb[4][2];
    #pragma unroll
    for (int p = 0; p < 4; ++p) {                  // prologue: 8 loads in flight
      pb[p][0] = *(const f32x4*)(ap + p * 32);
      pb[p][1] = *(const f32x4*)(ap + p * 32 + 4);
    }
    #pragma unroll 8
    for (int ks = 0; ks < 64; ++ks) {
      const int p = ks & 3;                        // static after unroll-8
      short8 A = cvt8v(pb[p][0], pb[p][1]);
      if (ks < 60) {                               // refill slot p for ks+4
        pb[p][0] = *(const f32x4*)(ap + (ks + 4) * 32);
        pb[p][1] = *(const f32x4*)(ap + (ks + 4) * 32 + 4);
      }
      #pragma unroll
      for (int at = 0; at < 4; ++at)
        qacc[at] = MFMA16(A, *(const short8*)(wqb + (size_t)(at * 64 + ks) * 512), qacc[at]);
    }
    #pragma unroll
    for (int at = 0; at < 4; ++at)
      #pragma unroll
      for (int r = 0; r < 4; ++r)                  // fold 1/sqrt(64) into Q
        qs[(hi * 4 + r) * 68 + at * 16 + lo] = qacc[at][r] * 0.125f;
  }

  // ---- Phase 2: scores = Q @ K^T. Load ALL 16 K fragments first ----
  f32x4 sacc[8];
  {
    short8 afrag[2];
    #pragma unroll
    for (int ks = 0; ks < 2; ++ks) {
      const float* qp = qs + lo * 68 + ks * 32 + hi * 8;
      afrag[ks] = cvt8v(*(const f32x4*)qp, *(const f32x4*)(qp + 4));
    }
    const unsigned short* kf = KF + ((size_t)lb * 16) * 512 + lane * 8;
    short8 kfr[8][2];
    #pragma unroll
    for (int nt = 0; nt < 8; ++nt) {
      kfr[nt][0] = *(const short8*)(kf + (size_t)nt * 1024);
      kfr[nt][1] = *(const short8*)(kf + (size_t)nt * 1024 + 512);
    }
    #pragma unroll
    for (int nt = 0; nt < 8; ++nt) {
      f32x4 a0 = (f32x4){0.f, 0.f, 0.f, 0.f};
      a0 = MFMA16(afrag[0], kfr[nt][0], a0);
      sacc[nt] = MFMA16(afrag[1], kfr[nt][1], a0);
    }
  }

  // ---- Phase 3: in-register softmax (row = hi*4+r, cols over lo) ----
  {
    #pragma unroll
    for (int r = 0; r < 4; ++r) {
      float m = sacc[0][r];
      #pragma unroll
      for (int nt = 1; nt < 8; ++nt) m = fmaxf(m, sacc[nt][r]);
      m = fmaxf(m, __shfl_xor(m, 1)); m = fmaxf(m, __shfl_xor(m, 2));
      m = fmaxf(m, __shfl_xor(m, 4)); m = fmaxf(m, __shfl_xor(m, 8));
      float s = 0.f;
      #pragma unroll
      for (int nt = 0; nt < 8; ++nt) {
        float e = __expf(sacc[nt][r] - m);
        sacc[nt][r] = e; s += e;
      }
      s += __shfl_xor(s, 1); s += __shfl_xor(s, 2);
      s += __shfl_xor(s, 4); s += __shfl_xor(s, 8);
      float inv = 1.0f / s;
      #pragma unroll
      for (int nt = 0; nt < 8; ++nt) sacc[nt][r] *= inv;
    }
    #pragma unroll
    for (int nt = 0; nt < 8; ++nt)                 // P bf16 [16][136], 272 B/row
      #pragma unroll
      for (int r = 0; r < 4; ++r)
        qsu[(hi * 4 + r) * 136 + nt * 16 + lo] = f2bf(sacc[nt][r]);
  }

  // ---- Phase 4: attn_out = P @ V. Load ALL 16 V fragments first ----
  {
    short8 pfrag[4];
    #pragma unroll
    for (int ks = 0; ks < 4; ++ks)
      pfrag[ks] = *(const short8*)((const char*)qs + lo * 272 + ks * 64 + hi * 16);
    const unsigned short* vf = VF + ((size_t)lb * 16) * 512 + lane * 8;
    short8 vfr[16];
    #pragma unroll
    for (int q = 0; q < 16; ++q)
      vfr[q] = *(const short8*)(vf + (size_t)q * 512);
    f32x4 ao[4];
    #pragma unroll
    for (int at = 0; at < 4; ++at) {
      f32x4 a = (f32x4){0.f, 0.f, 0.f, 0.f};
      #pragma unroll
      for (int ks = 0; ks < 4; ++ks)
        a = MFMA16(pfrag[ks], vfr[at * 4 + ks], a);
      ao[at] = a;
    }
    #pragma unroll
    for (int at = 0; at < 4; ++at)
      #pragma unroll
      for (int r = 0; r < 4; ++r)
        qs[(hi * 4 + r) * 68 + at * 16 + lo] = ao[at][r];
  }

  // ---- Phase 5: resid^T = Wo @ attn_out^T; depth-4-group pipeline ----
  {
    short8 bfrag[2];
    #pragma unroll
    for (int ks = 0; ks < 2; ++ks) {
      const float* ap2 = qs + lo * 68 + ks * 32 + hi * 8;
      bfrag[ks] = cvt8v(*(const f32x4*)ap2, *(const f32x4*)(ap2 + 4));
    }
    const unsigned short* wob = WoF + ((size_t)l * 256) * 512 + lane * 8;
    const float* hrow = hsrc + (size_t)lo * 2048 + hi * 4;
    float* orow = out + hbase + (size_t)lo * 2048 + hi * 4;
    short8 wo0[4], wo1[4];
    f32x4 hvb[4];
    #pragma unroll
    for (int j = 0; j < 4; ++j) {                  // prologue: group 0
      wo0[j] = *(const short8*)(wob + (size_t)j * 1024);
      wo1[j] = *(const short8*)(wob + (size_t)j * 1024 + 512);
      hvb[j] = *(const f32x4*)(hrow + j * 16);
    }
    #pragma unroll 1
    for (int g = 0; g < 32; ++g) {
      #pragma unroll
      for (int j = 0; j < 4; ++j) {
        int dt = g * 4 + j;
        short8 A0 = wo0[j], A1 = wo1[j];
        f32x4 h = hvb[j];
        if (g < 31) {                              // refill slot j for dt+4
          wo0[j] = *(const short8*)(wob + (size_t)(dt + 4) * 1024);
          wo1[j] = *(const short8*)(wob + (size_t)(dt + 4) * 1024 + 512);
          hvb[j] = *(const f32x4*)(hrow + (dt + 4) * 16);
        }
        f32x4 acc = (f32x4){0.f, 0.f, 0.f, 0.f};
        acc = MFMA16(A0, bfrag[0], acc);
        acc = MFMA16(A1, bfrag[1], acc);
        f32x4 o;
        #pragma unroll
        for (int r = 0; r < 4; ++r) o[r] = h[r] + gate * acc[r];
        __builtin_nontemporal_store(o, (f32x4*)(orow + dt * 16));
      }
    }
  }
}

extern "C" void kernel_launch(void* const* d_in, const int* in_sizes, int n_in,
                              void* d_out, int out_size, void* d_ws, size_t ws_size,
                              hipStream_t stream) {
  const float* hidden = (const float*)d_in[0];
  const float* bank   = (const float*)d_in[1];
  const float* Wq     = (const float*)d_in[2];
  const float* Wk     = (const float*)d_in[3];
  const float* Wv     = (const float*)d_in[4];
  const float* Wo     = (const float*)d_in[5];
  const float* gates  = (const float*)d_in[6];
  float* out = (float*)d_out;

  char* ws = (char*)d_ws;
  unsigned short* KF  = (unsigned short*)(ws);
  unsigned short* VF  = (unsigned short*)(ws + 262144);
  unsigned short* WqF = (unsigned short*)(ws + 524288);
  unsigned short* WoF = (unsigned short*)(ws + 2621440);

  pre_kv_kernel<<<256, 64, 0, stream>>>(bank, Wk, Wv, KF, VF);
  pre_frag_kernel<<<1024, 256, 0, stream>>>(Wq, Wo, WqF, WoF);
  adapter_main<<<1024, 256, 0, stream>>>(hidden, KF, VF, WqF, WoF, gates, out);
}

// Round 6
// 397.464 us; speedup vs baseline: 1.3258x; 1.3258x over previous
//
#include <hip/hip_runtime.h>
#include <cstdint>
#include <cstddef>

// SummaryAdapter fused kernel for MI355X (gfx950), v6: hidden streamed via
// async global_load_lds double-buffered 8KB chunks (pre-swizzled source),
// counted vmcnt(2) + raw s_barrier so DMA stays in flight across barriers.
// Both Q-phase and epilogue stream h; 29KB LDS -> 5 blocks/CU.
// L=8 B=2 S=4096 D=2048 N=128 Ds=1024 Da=64.
//
// Workspace layout (bytes):          off      size
//   KF  frag bf16                      0    262144
//   VF  frag bf16                 262144    262144
//   WqF frag bf16                 524288   2097152
//   WoF frag bf16                2621440   2097152
// Requires ws_size >= 4718592.

typedef __attribute__((ext_vector_type(8))) short short8;   // 8 x bf16
typedef __attribute__((ext_vector_type(4))) float f32x4;

#define MFMA16(a, b, c) __builtin_amdgcn_mfma_f32_16x16x32_bf16((a), (b), (c), 0, 0, 0)
#define WAITV2 asm volatile("s_waitcnt vmcnt(2)" ::: "memory")
#define WAITV0 asm volatile("s_waitcnt vmcnt(0)" ::: "memory")
#define BAR    __builtin_amdgcn_s_barrier()

__device__ __forceinline__ unsigned short f2bf(float f) {
  unsigned int x = __builtin_bit_cast(unsigned int, f);
  x += 0x7fffu + ((x >> 16) & 1u);        // RNE
  return (unsigned short)(x >> 16);
}
__device__ __forceinline__ short8 cvt8v(f32x4 a, f32x4 b) {
  short8 r;
  r[0] = (short)f2bf(a[0]); r[1] = (short)f2bf(a[1]);
  r[2] = (short)f2bf(a[2]); r[3] = (short)f2bf(a[3]);
  r[4] = (short)f2bf(b[0]); r[5] = (short)f2bf(b[1]);
  r[6] = (short)f2bf(b[2]); r[7] = (short)f2bf(b[3]);
  return r;
}
__device__ __forceinline__ short8 ld_cvt8(const float* p) {
  f32x4 v0 = *(const f32x4*)p, v1 = *(const f32x4*)(p + 4);
  return cvt8v(v0, v1);
}
// async 16B/lane global->LDS DMA; lds base wave-uniform, global per-lane
__device__ __forceinline__ void gload_lds16(const void* g, void* l) {
  typedef __attribute__((address_space(1))) const unsigned int gu32;
  typedef __attribute__((address_space(3))) unsigned int lu32;
  __builtin_amdgcn_global_load_lds((gu32*)(const unsigned int*)g,
                                   (lu32*)(unsigned int*)l, 16, 0, 0);
}

// ---------------- pre 1: K = bank@Wk^T, V = bank@Wv^T via MFMA -------------
// 1024 one-wave blocks: bid = (((l*2+b)*2+kv)*8+nt)*4+at.
__global__ __launch_bounds__(64)
void pre_kv_kernel(const float* __restrict__ bank,
                   const float* __restrict__ Wk,
                   const float* __restrict__ Wv,
                   unsigned short* __restrict__ KF, unsigned short* __restrict__ VF) {
  int bid = blockIdx.x;
  int at = bid & 3, nt = (bid >> 2) & 7, kv = (bid >> 5) & 1;
  int b = (bid >> 6) & 1, l = bid >> 7;
  int lane = threadIdx.x & 63;
  int lo = lane & 15, hi = lane >> 4;
  const float* W  = (kv ? Wv : Wk) + (size_t)l * 65536;
  const float* bk = bank + (size_t)b * 131072;
  int lbq = l * 2 + b;
  f32x4 acc = (f32x4){0.f, 0.f, 0.f, 0.f};
  for (int ks = 0; ks < 32; ++ks) {
    short8 A = ld_cvt8(bk + (nt * 16 + lo) * 1024 + ks * 32 + hi * 8);
    short8 B = ld_cvt8(W + (at * 16 + lo) * 1024 + ks * 32 + hi * 8);
    acc = MFMA16(A, B, acc);
  }
  for (int r = 0; r < 4; ++r) {
    int n = nt * 16 + hi * 4 + r;
    int a = at * 16 + lo;
    unsigned short v = f2bf(acc[r]);
    if (kv == 0) {
      int idx = ((lbq * 8 + (n >> 4)) * 2 + (a >> 5)) * 512 +
                (((a >> 3) & 3) * 16 + (n & 15)) * 8 + (a & 7);
      KF[idx] = v;
    } else {
      int idx = ((lbq * 4 + (a >> 4)) * 4 + (n >> 5)) * 512 +
                (((n >> 3) & 3) * 16 + (a & 15)) * 8 + (n & 7);
      VF[idx] = v;
    }
  }
}

// ---------------- pre 2: Wq/Wo -> bf16 fragment layout ---------------------
__global__ void pre_frag_kernel(const float* __restrict__ Wq, const float* __restrict__ Wo,
                                unsigned short* __restrict__ WqF, unsigned short* __restrict__ WoF) {
  int idx = blockIdx.x * 256 + threadIdx.x;        // 262144 threads
  if (idx < 131072) {
    int t = idx;
    int lane = t & 63, ks = (t >> 6) & 63, at = (t >> 12) & 3, l = t >> 14;
    int a = at * 16 + (lane & 15), d = ks * 32 + (lane >> 4) * 8;
    *(short8*)(WqF + (size_t)t * 8) = ld_cvt8(Wq + ((size_t)(l * 64 + a)) * 2048 + d);
  } else {
    int t = idx - 131072;
    int lane = t & 63, ks = (t >> 6) & 1, dt = (t >> 7) & 127, l = t >> 14;
    int d = dt * 16 + (lane & 15), a = ks * 32 + (lane >> 4) * 8;
    *(short8*)(WoF + (size_t)t * 8) = ld_cvt8(Wo + ((size_t)(l * 2048 + d)) * 64 + a);
  }
}

// ---------------- main fused kernel ----------------------------------------
// 4096 blocks x 256 threads (4 waves), block owns one 16-row s-tile.
// LDS 29184 B -> 5 blocks/CU. h streamed twice (Q + epilogue) through
// stage[2][8KB] via global_load_lds; chunk = 16 rows x 128 f32 cols.
// Source pre-swizzled (byte ^ (row&7)<<4 within 512B row) => conflict-free
// ds_read_b128 on consumption; LDS dest linear as gll requires.
__global__ __launch_bounds__(256, 5)
void adapter_main(const float* __restrict__ hidden,
                  const unsigned short* __restrict__ KF, const unsigned short* __restrict__ VF,
                  const unsigned short* __restrict__ WqF, const unsigned short* __restrict__ WoF,
                  const float* __restrict__ gates, float* __restrict__ out) {
  __shared__ __align__(16) char stage[16384];          // 2 x 16 rows x 512 B
  __shared__ float qb[16 * 132];                       // Q/scores/attn_out
  __shared__ __align__(16) unsigned short pb[16 * 136];// P bf16, 272 B/row

  // XCD-bijective swizzle: XCD x gets 512 consecutive tiles = layer x.
  int bid0 = blockIdx.x;
  int bid = (bid0 & 7) * 512 + (bid0 >> 3);
  int st = bid & 255, b = (bid >> 8) & 1, l = bid >> 9;
  int tid = threadIdx.x, wave = tid >> 6, lane = tid & 63;
  int lo = lane & 15, hi = lane >> 4;
  int swlo = (lo & 7) << 4;
  size_t hbase = ((size_t)(l * 2 + b) * 4096 + st * 16) * 2048;
  const char* hbytes = (const char*)(hidden + hbase);
  float gate = 1.0f / (1.0f + __expf(-gates[l]));
  int lb = l * 2 + b;
  int at = wave;

  // staging geometry: instr q (=wave*2+j) covers rows 2q..2q+1
  int q0 = wave * 2;
  int srow0 = q0 * 2 + (lane >> 5);
  int srow1 = srow0 + 2;
  int scolb = (lane & 31) * 16;
  size_t goff0 = (size_t)srow0 * 8192 + (size_t)(scolb ^ ((srow0 & 7) << 4));
  size_t goff1 = (size_t)srow1 * 8192 + (size_t)(scolb ^ ((srow1 & 7) << 4));
  char* stg = (char*)stage;

#define STAGE_CHUNK(c, buf)                                                    \
  do {                                                                         \
    gload_lds16(hbytes + (size_t)(c) * 512 + goff0, stg + (buf) * 8192 + q0 * 1024);        \
    gload_lds16(hbytes + (size_t)(c) * 512 + goff1, stg + (buf) * 8192 + q0 * 1024 + 1024); \
  } while (0)

  // ---- Phase 1: Q = h @ Wq^T, streaming 16 chunks of 16x128 f32 ----
  f32x4 qacc = (f32x4){0.f, 0.f, 0.f, 0.f};
  {
    const unsigned short* wqb = WqF + ((size_t)(l * 4 + at) * 64) * 512 + lane * 8;
    STAGE_CHUNK(0, 0);
    STAGE_CHUNK(1, 1);
    #pragma unroll 1
    for (int c = 0; c < 16; ++c) {
      if (c < 15) { WAITV2; } else { WAITV0; }
      BAR;                                           // chunk c ready for all
      const char* sb = stg + (c & 1) * 8192 + lo * 512;
      #pragma unroll
      for (int ks2 = 0; ks2 < 4; ++ks2) {
        int cb = ks2 * 128 + hi * 32;
        f32x4 v0 = *(const f32x4*)(sb + (cb ^ swlo));
        f32x4 v1 = *(const f32x4*)(sb + ((cb + 16) ^ swlo));
        short8 A = cvt8v(v0, v1);
        short8 B = *(const short8*)(wqb + (size_t)(at * 64 + c * 4 + ks2) * 512);
        qacc = MFMA16(A, B, qacc);
      }
      BAR;                                           // all reads of buf done
      if (c < 14) STAGE_CHUNK(c + 2, c & 1);
    }
  }

  // prefetch epilogue chunks 0,1 now: overlaps attention middle phases
  STAGE_CHUNK(0, 0);
  STAGE_CHUNK(1, 1);

  // write Q (scaled) to qb
  #pragma unroll
  for (int r = 0; r < 4; ++r)
    qb[(hi * 4 + r) * 132 + at * 16 + lo] = qacc[r] * 0.125f;
  __syncthreads();

  // ---- Phase 2: afrag from Q; scores = Q @ K^T ----
  short8 afrag[2];
  #pragma unroll
  for (int ks = 0; ks < 2; ++ks) {
    const float* qp = qb + lo * 132 + ks * 32 + hi * 8;
    afrag[ks] = cvt8v(*(const f32x4*)qp, *(const f32x4*)(qp + 4));
  }
  __syncthreads();
  #pragma unroll
  for (int i = 0; i < 2; ++i) {
    int nt = wave * 2 + i;
    f32x4 acc = (f32x4){0.f, 0.f, 0.f, 0.f};
    const unsigned short* kf = KF + ((size_t)(lb * 8 + nt) * 2) * 512 + lane * 8;
    acc = MFMA16(afrag[0], *(const short8*)(kf), acc);
    acc = MFMA16(afrag[1], *(const short8*)(kf + 512), acc);
    #pragma unroll
    for (int r = 0; r < 4; ++r)
      qb[(hi * 4 + r) * 132 + nt * 16 + lo] = acc[r];
  }
  __syncthreads();

  // ---- Phase 3: softmax over N=128 (16 lanes per row) -> P bf16 ----
  {
    int row = wave * 4 + hi;
    const float* sp = qb + row * 132 + lo * 8;
    f32x4 v0 = *(const f32x4*)sp, v1 = *(const f32x4*)(sp + 4);
    float m = fmaxf(fmaxf(fmaxf(v0[0], v0[1]), fmaxf(v0[2], v0[3])),
                    fmaxf(fmaxf(v1[0], v1[1]), fmaxf(v1[2], v1[3])));
    m = fmaxf(m, __shfl_xor(m, 1)); m = fmaxf(m, __shfl_xor(m, 2));
    m = fmaxf(m, __shfl_xor(m, 4)); m = fmaxf(m, __shfl_xor(m, 8));
    f32x4 e0, e1; float s = 0.f;
    #pragma unroll
    for (int j = 0; j < 4; ++j) { e0[j] = __expf(v0[j] - m); s += e0[j]; }
    #pragma unroll
    for (int j = 0; j < 4; ++j) { e1[j] = __expf(v1[j] - m); s += e1[j]; }
    s += __shfl_xor(s, 1); s += __shfl_xor(s, 2);
    s += __shfl_xor(s, 4); s += __shfl_xor(s, 8);
    float inv = 1.0f / s;
    #pragma unroll
    for (int j = 0; j < 4; ++j) { e0[j] *= inv; e1[j] *= inv; }
    *(short8*)((char*)pb + row * 272 + lo * 16) = cvt8v(e0, e1);
  }
  __syncthreads();

  // ---- Phase 4: attn_out = P @ V -> qb ----
  {
    short8 pfrag[4];
    #pragma unroll
    for (int ks = 0; ks < 4; ++ks)
      pfrag[ks] = *(const short8*)((const char*)pb + lo * 272 + ks * 64 + hi * 16);
    const unsigned short* vf = VF + ((size_t)(lb * 4 + at) * 4) * 512 + lane * 8;
    f32x4 a = (f32x4){0.f, 0.f, 0.f, 0.f};
    #pragma unroll
    for (int ks = 0; ks < 4; ++ks)
      a = MFMA16(pfrag[ks], *(const short8*)(vf + (size_t)ks * 512), a);
    #pragma unroll
    for (int r = 0; r < 4; ++r)
      qb[(hi * 4 + r) * 132 + at * 16 + lo] = a[r];
  }
  __syncthreads();

  // ---- Phase 5: epilogue, streaming h again; out = h + gate*(Wo@ao^T) ----
  {
    short8 bfrag[2];
    #pragma unroll
    for (int ks = 0; ks < 2; ++ks) {
      const float* ap2 = qb + lo * 132 + ks * 32 + hi * 8;
      bfrag[ks] = cvt8v(*(const f32x4*)ap2, *(const f32x4*)(ap2 + 4));
    }
    float* orow = out + hbase;
    #pragma unroll 1
    for (int c = 0; c < 16; ++c) {
      if (c < 15) { WAITV2; } else { WAITV0; }
      BAR;                                           // chunk c staged
      const char* sb = stg + (c & 1) * 8192 + lo * 512;
      #pragma unroll
      for (int j = 0; j < 2; ++j) {
        int dt = c * 8 + wave * 2 + j;
        const unsigned short* wo = WoF + ((size_t)(l * 128 + dt) * 2) * 512 + lane * 8;
        short8 A0 = *(const short8*)(wo);
        short8 A1 = *(const short8*)(wo + 512);
        f32x4 acc = (f32x4){0.f, 0.f, 0.f, 0.f};
        acc = MFMA16(A0, bfrag[0], acc);
        acc = MFMA16(A1, bfrag[1], acc);
        int cb = (wave * 2 + j) * 64 + hi * 16;
        f32x4 hv = *(const f32x4*)(sb + (cb ^ swlo));
        f32x4 o;
        #pragma unroll
        for (int r = 0; r < 4; ++r) o[r] = hv[r] + gate * acc[r];
        *(f32x4*)(orow + (size_t)lo * 2048 + dt * 16 + hi * 4) = o;
      }
      BAR;                                           // buf reads done
      if (c < 14) STAGE_CHUNK(c + 2, c & 1);
    }
  }
#undef STAGE_CHUNK
}

extern "C" void kernel_launch(void* const* d_in, const int* in_sizes, int n_in,
                              void* d_out, int out_size, void* d_ws, size_t ws_size,
                              hipStream_t stream) {
  const float* hidden = (const float*)d_in[0];
  const float* bank   = (const float*)d_in[1];
  const float* Wq     = (const float*)d_in[2];
  const float* Wk     = (const float*)d_in[3];
  const float* Wv     = (const float*)d_in[4];
  const float* Wo     = (const float*)d_in[5];
  const float* gates  = (const float*)d_in[6];
  float* out = (float*)d_out;

  char* ws = (char*)d_ws;
  unsigned short* KF  = (unsigned short*)(ws);
  unsigned short* VF  = (unsigned short*)(ws + 262144);
  unsigned short* WqF = (unsigned short*)(ws + 524288);
  unsigned short* WoF = (unsigned short*)(ws + 2621440);

  pre_kv_kernel<<<1024, 64, 0, stream>>>(bank, Wk, Wv, KF, VF);
  pre_frag_kernel<<<1024, 256, 0, stream>>>(Wq, Wo, WqF, WoF);
  adapter_main<<<4096, 256, 0, stream>>>(hidden, KF, VF, WqF, WoF, gates, out);
}